// Round 1
// baseline (2411.884 us; speedup 1.0000x reference)
//
#include <hip/hip_runtime.h>
#include <math.h>

static constexpr int BATCH = 64;
static constexpr int SEQ   = 32;
static constexpr int TOK   = BATCH * SEQ;   // 2048
static constexpr int DIM   = 1024;
static constexpr int NH    = 16;
static constexpr int HDIM  = 64;
static constexpr int FFD   = 2048;
static constexpr int LAYERS= 4;
static constexpr int NHEAD_OUT = 26;
static constexpr int IDH   = 512;

// ---------------- block-wide sum (256 threads = 4 waves) ----------------
__device__ __forceinline__ float block_sum(float v, float* red) {
    #pragma unroll
    for (int off = 32; off > 0; off >>= 1) v += __shfl_down(v, off);
    int lane = threadIdx.x & 63;
    int w    = threadIdx.x >> 6;
    if (lane == 0) red[w] = v;
    __syncthreads();
    float t = red[0] + red[1] + red[2] + red[3];
    __syncthreads();
    return t;
}

// ---------------- LayerNorm: optional pre non-affine LN(1e-6), then affine LN(1e-5)
template<bool PRE>
__global__ __launch_bounds__(256) void ln_kernel(const float* __restrict__ x,
                                                 const float* __restrict__ g,
                                                 const float* __restrict__ b,
                                                 float* __restrict__ y) {
    __shared__ float red[4];
    long row = blockIdx.x;
    const float* xr = x + row * DIM;
    int tid = threadIdx.x;
    float4 v = *(const float4*)(xr + tid * 4);
    if (PRE) {
        float s  = block_sum(v.x + v.y + v.z + v.w, red);
        float mu = s * (1.0f / DIM);
        v.x -= mu; v.y -= mu; v.z -= mu; v.w -= mu;
        float ss = block_sum(v.x*v.x + v.y*v.y + v.z*v.z + v.w*v.w, red);
        float r  = 1.0f / sqrtf(ss * (1.0f / DIM) + 1e-6f);
        v.x *= r; v.y *= r; v.z *= r; v.w *= r;
    }
    float s  = block_sum(v.x + v.y + v.z + v.w, red);
    float mu = s * (1.0f / DIM);
    v.x -= mu; v.y -= mu; v.z -= mu; v.w -= mu;
    float ss = block_sum(v.x*v.x + v.y*v.y + v.z*v.z + v.w*v.w, red);
    float r  = 1.0f / sqrtf(ss * (1.0f / DIM) + 1e-5f);
    float4 gg = *(const float4*)(g + tid * 4);
    float4 bb = *(const float4*)(b + tid * 4);
    float4 o;
    o.x = v.x * r * gg.x + bb.x;
    o.y = v.y * r * gg.y + bb.y;
    o.z = v.z * r * gg.z + bb.z;
    o.w = v.w * r * gg.w + bb.w;
    *(float4*)(y + row * DIM + tid * 4) = o;
}

// ---------------- tiled fp32 GEMM, 64x64 tile, BK=16, 256 thr, 4x4 micro-tile
// EPI: 0 = none, 1 = +bias +residual, 2 = +bias then exact gelu, 3 = +bias then relu
template<int EPI>
__global__ __launch_bounds__(256) void gemm64(const float* __restrict__ A,
                                              const float* __restrict__ Bm,
                                              const float* __restrict__ bias,
                                              const float* __restrict__ resid,
                                              float* __restrict__ C,
                                              int M, int N, int K,
                                              long sA, long sB, long sbias, long sC) {
    int g = blockIdx.z;
    A  += (long)g * sA;
    Bm += (long)g * sB;
    C  += (long)g * sC;
    if (EPI != 0) bias += (long)g * sbias;

    __shared__ float As[16][64];
    __shared__ float Bs[16][64];
    int tid = threadIdx.x;
    int tx = tid & 15, ty = tid >> 4;
    int m0 = blockIdx.y * 64, n0 = blockIdx.x * 64;

    float acc[4][4] = {};

    int am = tid >> 2;            // 0..63
    int ak = (tid & 3) << 2;      // 0,4,8,12
    int bk = tid >> 4;            // 0..15
    int bn = (tid & 15) << 2;     // 0..60
    const float* Ap = A  + (long)(m0 + am) * K + ak;
    const float* Bp = Bm + (long)bk * N + n0 + bn;

    for (int k0 = 0; k0 < K; k0 += 16) {
        float4 a = *(const float4*)(Ap + k0);
        As[ak + 0][am] = a.x;
        As[ak + 1][am] = a.y;
        As[ak + 2][am] = a.z;
        As[ak + 3][am] = a.w;
        *(float4*)&Bs[bk][bn] = *(const float4*)(Bp + (long)k0 * N);
        __syncthreads();
        #pragma unroll
        for (int k = 0; k < 16; ++k) {
            float av[4], bv[4];
            #pragma unroll
            for (int i = 0; i < 4; ++i) av[i] = As[k][ty * 4 + i];
            #pragma unroll
            for (int j = 0; j < 4; ++j) bv[j] = Bs[k][tx * 4 + j];
            #pragma unroll
            for (int i = 0; i < 4; ++i)
                #pragma unroll
                for (int j = 0; j < 4; ++j)
                    acc[i][j] = fmaf(av[i], bv[j], acc[i][j]);
        }
        __syncthreads();
    }

    #pragma unroll
    for (int i = 0; i < 4; ++i) {
        int m = m0 + ty * 4 + i;
        #pragma unroll
        for (int j = 0; j < 4; ++j) {
            int n = n0 + tx * 4 + j;
            float v = acc[i][j];
            if (EPI != 0) v += bias[n];
            if (EPI == 2) v = 0.5f * v * (1.0f + erff(v * 0.70710678118654752f));
            if (EPI == 3) v = fmaxf(v, 0.0f);
            if (EPI == 1) v += resid[(long)m * N + n];
            C[(long)m * N + n] = v;
        }
    }
}

// ---------------- fused attention: one block per (batch, head). T=32, HD=64.
__global__ __launch_bounds__(256) void attn_kernel(const float* __restrict__ qkv,
                                                   float* __restrict__ o) {
    int bh = blockIdx.x;
    int b  = bh >> 4;
    int hh = bh & 15;
    __shared__ float qs[32][64];
    __shared__ float kt[64][33];   // transposed K, padded: conflict-free QK reads
    __shared__ float vs[32][64];
    __shared__ float ps[32][33];
    const float* base = qkv + (long)b * SEQ * (3 * DIM) + hh * HDIM;
    int tid = threadIdx.x;

    for (int i = tid; i < 512; i += 256) {     // 32*64/4 float4 loads per matrix
        int t = i >> 4;
        int c = (i & 15) << 2;
        *(float4*)&qs[t][c] = *(const float4*)(base + (long)t * 3 * DIM + c);
        float4 kv = *(const float4*)(base + (long)t * 3 * DIM + DIM + c);
        kt[c + 0][t] = kv.x;
        kt[c + 1][t] = kv.y;
        kt[c + 2][t] = kv.z;
        kt[c + 3][t] = kv.w;
        *(float4*)&vs[t][c] = *(const float4*)(base + (long)t * 3 * DIM + 2 * DIM + c);
    }
    __syncthreads();

    for (int i = tid; i < 1024; i += 256) {    // scores 32x32
        int r = i >> 5, c = i & 31;
        float acc = 0.f;
        #pragma unroll
        for (int d = 0; d < 64; ++d) acc = fmaf(qs[r][d], kt[d][c], acc);
        ps[r][c] = acc * 0.125f;
    }
    __syncthreads();

    if (tid < 32) {                            // softmax per row
        float mx = -1e30f;
        for (int c = 0; c < 32; ++c) mx = fmaxf(mx, ps[tid][c]);
        float sum = 0.f;
        for (int c = 0; c < 32; ++c) { float e = expf(ps[tid][c] - mx); ps[tid][c] = e; sum += e; }
        float inv = 1.f / sum;
        for (int c = 0; c < 32; ++c) ps[tid][c] *= inv;
    }
    __syncthreads();

    for (int i = tid; i < 2048; i += 256) {    // O = P @ V, 32x64
        int r = i >> 6, d = i & 63;
        float acc = 0.f;
        #pragma unroll
        for (int c = 0; c < 32; ++c) acc = fmaf(ps[r][c], vs[c][d], acc);
        o[(long)b * SEQ * DIM + (long)r * DIM + hh * HDIM + d] = acc;
    }
}

// ---------------- x_comb: concat(x[:,0,:], x[:,1,:]) == first 2048 floats of each batch
__global__ void comb_kernel(const float* __restrict__ h, float* __restrict__ xc) {
    int i = blockIdx.x * 256 + threadIdx.x;    // 64*2048 total
    int b = i >> 11;
    int c = i & 2047;
    xc[i] = h[(long)b * (SEQ * DIM) + c];
}

// ---------------- head layer 3: one wave per (n, b), dot-512
__global__ __launch_bounds__(256) void head3_kernel(const float* __restrict__ h2,
                                                    const float* __restrict__ w3,
                                                    const float* __restrict__ b3,
                                                    float* __restrict__ out) {
    int gid  = blockIdx.x * 256 + threadIdx.x;
    int wave = gid >> 6;
    int lane = gid & 63;
    if (wave >= NHEAD_OUT * BATCH) return;
    int n = wave >> 6;      // /64
    int b = wave & 63;
    const float* a = h2 + ((long)n * BATCH + b) * IDH;
    const float* w = w3 + (long)n * IDH;
    float acc = 0.f;
    #pragma unroll
    for (int i = lane; i < IDH; i += 64) acc = fmaf(a[i], w[i], acc);
    #pragma unroll
    for (int off = 32; off > 0; off >>= 1) acc += __shfl_down(acc, off);
    if (lane == 0) out[b * NHEAD_OUT + n] = acc + b3[n];
}

extern "C" void kernel_launch(void* const* d_in, const int* in_sizes, int n_in,
                              void* d_out, int out_size, void* d_ws, size_t ws_size,
                              hipStream_t stream) {
    const float* x      = (const float*)d_in[0];
    const float* qkv_w  = (const float*)d_in[1];
    const float* out_w  = (const float*)d_in[2];
    const float* out_b  = (const float*)d_in[3];
    const float* attn_g = (const float*)d_in[4];
    const float* attn_b = (const float*)d_in[5];
    const float* ff_g   = (const float*)d_in[6];
    const float* ff_b   = (const float*)d_in[7];
    const float* ff_w1  = (const float*)d_in[8];
    const float* ff_b1  = (const float*)d_in[9];
    const float* ff_w2  = (const float*)d_in[10];
    const float* ff_b2  = (const float*)d_in[11];
    const float* hw1    = (const float*)d_in[12];
    const float* hb1    = (const float*)d_in[13];
    const float* hw2    = (const float*)d_in[14];
    const float* hb2    = (const float*)d_in[15];
    const float* hw3    = (const float*)d_in[16];
    const float* hb3    = (const float*)d_in[17];
    float* out = (float*)d_out;

    float* ws   = (float*)d_ws;
    float* h    = ws;                          // 2048*1024
    float* y    = h    + (long)TOK * DIM;      // 2048*1024
    float* qkvb = y    + (long)TOK * DIM;      // 2048*3072 (reused as ff buffer)
    float* ob   = qkvb + (long)TOK * 3 * DIM;  // 2048*1024
    float* xc   = ob   + (long)TOK * DIM;      // 64*2048
    float* h1   = xc   + (long)BATCH * 2 * DIM;        // 26*64*512
    float* h2   = h1   + (long)NHEAD_OUT * BATCH * IDH;
    float* ffb  = qkvb;

    hipMemcpyAsync(h, x, (size_t)TOK * DIM * sizeof(float),
                   hipMemcpyDeviceToDevice, stream);

    for (int l = 0; l < LAYERS; ++l) {
        ln_kernel<true><<<TOK, 256, 0, stream>>>(h, attn_g + l * DIM, attn_b + l * DIM, y);
        gemm64<0><<<dim3(3 * DIM / 64, TOK / 64, 1), 256, 0, stream>>>(
            y, qkv_w + (long)l * DIM * 3 * DIM, nullptr, nullptr, qkvb,
            TOK, 3 * DIM, DIM, 0, 0, 0, 0);
        attn_kernel<<<BATCH * NH, 256, 0, stream>>>(qkvb, ob);
        gemm64<1><<<dim3(DIM / 64, TOK / 64, 1), 256, 0, stream>>>(
            ob, out_w + (long)l * DIM * DIM, out_b + l * DIM, h, h,
            TOK, DIM, DIM, 0, 0, 0, 0);
        ln_kernel<false><<<TOK, 256, 0, stream>>>(h, ff_g + l * DIM, ff_b + l * DIM, y);
        gemm64<2><<<dim3(FFD / 64, TOK / 64, 1), 256, 0, stream>>>(
            y, ff_w1 + (long)l * DIM * FFD, ff_b1 + l * FFD, nullptr, ffb,
            TOK, FFD, DIM, 0, 0, 0, 0);
        gemm64<1><<<dim3(DIM / 64, TOK / 64, 1), 256, 0, stream>>>(
            ffb, ff_w2 + (long)l * FFD * DIM, ff_b2 + l * DIM, h, h,
            TOK, DIM, FFD, 0, 0, 0, 0);
    }

    comb_kernel<<<(BATCH * 2 * DIM) / 256, 256, 0, stream>>>(h, xc);

    gemm64<3><<<dim3(IDH / 64, 1, NHEAD_OUT), 256, 0, stream>>>(
        xc, hw1, hb1, nullptr, h1,
        BATCH, IDH, 2 * DIM,
        0, (long)2 * DIM * IDH, IDH, (long)BATCH * IDH);
    gemm64<3><<<dim3(IDH / 64, 1, NHEAD_OUT), 256, 0, stream>>>(
        h1, hw2, hb2, nullptr, h2,
        BATCH, IDH, IDH,
        (long)BATCH * IDH, (long)IDH * IDH, IDH, (long)BATCH * IDH);
    head3_kernel<<<(NHEAD_OUT * BATCH * 64) / 256, 256, 0, stream>>>(h2, hw3, hb3, out);
}

// Round 2
// 796.753 us; speedup vs baseline: 3.0271x; 3.0271x over previous
//
#include <hip/hip_runtime.h>
#include <math.h>

static constexpr int BATCH = 64;
static constexpr int SEQ   = 32;
static constexpr int TOK   = BATCH * SEQ;   // 2048
static constexpr int DIM   = 1024;
static constexpr int NH    = 16;
static constexpr int HDIM  = 64;
static constexpr int FFD   = 2048;
static constexpr int LAYERS= 4;
static constexpr int NHEAD_OUT = 26;
static constexpr int IDH   = 512;

typedef __bf16 bf16_t;
typedef __bf16 bf16x8 __attribute__((ext_vector_type(8)));
typedef float  f32x4  __attribute__((ext_vector_type(4)));
typedef unsigned short us4 __attribute__((ext_vector_type(4)));

__device__ __forceinline__ unsigned short f2bfu(float f) {
    return __builtin_bit_cast(unsigned short, (bf16_t)f);
}

__device__ __forceinline__ void gload_lds16(const void* gp, void* lp) {
    __builtin_amdgcn_global_load_lds(
        (const __attribute__((address_space(1))) unsigned int*)gp,
        (__attribute__((address_space(3))) unsigned int*)lp,
        16, 0, 0);
}

// ---------------- block-wide sum (256 threads = 4 waves) ----------------
__device__ __forceinline__ float block_sum(float v, float* red) {
    #pragma unroll
    for (int off = 32; off > 0; off >>= 1) v += __shfl_down(v, off);
    int lane = threadIdx.x & 63;
    int w    = threadIdx.x >> 6;
    if (lane == 0) red[w] = v;
    __syncthreads();
    float t = red[0] + red[1] + red[2] + red[3];
    __syncthreads();
    return t;
}

// ---------------- LayerNorm -> bf16 output
template<bool PRE>
__global__ __launch_bounds__(256) void ln_kernel(const float* __restrict__ x,
                                                 const float* __restrict__ g,
                                                 const float* __restrict__ b,
                                                 bf16_t* __restrict__ y) {
    __shared__ float red[4];
    long row = blockIdx.x;
    const float* xr = x + row * DIM;
    int tid = threadIdx.x;
    float4 v = *(const float4*)(xr + tid * 4);
    if (PRE) {
        float s  = block_sum(v.x + v.y + v.z + v.w, red);
        float mu = s * (1.0f / DIM);
        v.x -= mu; v.y -= mu; v.z -= mu; v.w -= mu;
        float ss = block_sum(v.x*v.x + v.y*v.y + v.z*v.z + v.w*v.w, red);
        float r  = 1.0f / sqrtf(ss * (1.0f / DIM) + 1e-6f);
        v.x *= r; v.y *= r; v.z *= r; v.w *= r;
    }
    float s  = block_sum(v.x + v.y + v.z + v.w, red);
    float mu = s * (1.0f / DIM);
    v.x -= mu; v.y -= mu; v.z -= mu; v.w -= mu;
    float ss = block_sum(v.x*v.x + v.y*v.y + v.z*v.z + v.w*v.w, red);
    float r  = 1.0f / sqrtf(ss * (1.0f / DIM) + 1e-5f);
    float4 gg = *(const float4*)(g + tid * 4);
    float4 bb = *(const float4*)(b + tid * 4);
    us4 o;
    o.x = f2bfu(v.x * r * gg.x + bb.x);
    o.y = f2bfu(v.y * r * gg.y + bb.y);
    o.z = f2bfu(v.z * r * gg.z + bb.z);
    o.w = f2bfu(v.w * r * gg.w + bb.w);
    *(us4*)(y + row * DIM + tid * 4) = o;
}

// ---------------- transpose + fp32->bf16: W[K][N] -> WT[N][K], grouped over z
__global__ __launch_bounds__(256) void transpose_cvt(const float* __restrict__ W,
                                                     bf16_t* __restrict__ WT,
                                                     int K, int N) {
    long g = blockIdx.z;
    W  += g * (long)K * N;
    WT += g * (long)K * N;
    __shared__ float t[32][33];
    int n0 = blockIdx.x * 32, k0 = blockIdx.y * 32;
    int r = threadIdx.x >> 3;          // 0..31
    int c = (threadIdx.x & 7) * 4;     // 0,4,...,28
    float4 v = *(const float4*)(W + (long)(k0 + r) * N + n0 + c);
    t[r][c] = v.x; t[r][c+1] = v.y; t[r][c+2] = v.z; t[r][c+3] = v.w;
    __syncthreads();
    us4 o;
    o.x = f2bfu(t[c+0][r]);
    o.y = f2bfu(t[c+1][r]);
    o.z = f2bfu(t[c+2][r]);
    o.w = f2bfu(t[c+3][r]);
    *(us4*)(WT + (long)(n0 + r) * K + k0 + c) = o;
}

// ---------------- MFMA GEMM: A[M][K] bf16, BT[N][K] bf16, C = A @ B (+epilogue)
// EPI: 0 = none (fp32 out), 1 = +bias +resid (fp32 out),
//      2 = +bias, gelu (bf16 out), 3 = +bias, relu (bf16 out)
template<int BM, int BN, int WM, int WN, int EPI>
__global__ __launch_bounds__(256) void gemm_bt(
    const bf16_t* __restrict__ A, const bf16_t* __restrict__ BT,
    const float* __restrict__ bias, const float* __restrict__ resid,
    void* __restrict__ Cv,
    int M, int N, int K, long sA, long sB, long sbias, long sC)
{
    constexpr int WAVES_N = BN / WN;
    constexpr int FM = WM / 16, FN = WN / 16;
    long g = blockIdx.z;
    A  += g * sA;
    BT += g * sB;
    if (EPI != 0) bias += g * sbias;
    float*  Cf = (float*)Cv + g * sC;
    bf16_t* Ch = (bf16_t*)Cv + g * sC;

    __shared__ bf16_t As[BM * 32];
    __shared__ bf16_t Bs[BN * 32];

    int tid  = threadIdx.x;
    int wave = tid >> 6, lane = tid & 63;
    int wr = wave / WAVES_N, wc = wave % WAVES_N;
    int m0 = blockIdx.y * BM, n0 = blockIdx.x * BN;

    f32x4 acc[FM][FN];
    #pragma unroll
    for (int m = 0; m < FM; ++m)
        #pragma unroll
        for (int n = 0; n < FN; ++n)
            acc[m][n] = f32x4{0.f, 0.f, 0.f, 0.f};

    const char* Ab = (const char*)A;
    const char* Bb = (const char*)BT;
    char* AsB = (char*)As;
    char* BsB = (char*)Bs;
    long  rsb = (long)K * 2;   // row byte stride for A / BT

    int lr = lane & 15;
    int lk = (lane >> 4) * 8;

    for (int k0 = 0; k0 < K; k0 += 32) {
        long kb = (long)k0 * 2;
        #pragma unroll
        for (int i = 0; i < BM / 64; ++i) {
            int cb  = ((i * 4 + wave) * 64 + lane) * 16;
            int row = cb >> 6, col = cb & 63;
            gload_lds16(Ab + (long)(m0 + row) * rsb + kb + col,
                        AsB + (i * 4 + wave) * 1024);
        }
        #pragma unroll
        for (int i = 0; i < BN / 64; ++i) {
            int cb  = ((i * 4 + wave) * 64 + lane) * 16;
            int row = cb >> 6, col = cb & 63;
            gload_lds16(Bb + (long)(n0 + row) * rsb + kb + col,
                        BsB + (i * 4 + wave) * 1024);
        }
        __syncthreads();
        bf16x8 af[FM], bq[FN];
        #pragma unroll
        for (int m = 0; m < FM; ++m)
            af[m] = *(const bf16x8*)&As[(wr * WM + m * 16 + lr) * 32 + lk];
        #pragma unroll
        for (int n = 0; n < FN; ++n)
            bq[n] = *(const bf16x8*)&Bs[(wc * WN + n * 16 + lr) * 32 + lk];
        #pragma unroll
        for (int m = 0; m < FM; ++m)
            #pragma unroll
            for (int n = 0; n < FN; ++n)
                acc[m][n] = __builtin_amdgcn_mfma_f32_16x16x32_bf16(
                    af[m], bq[n], acc[m][n], 0, 0, 0);
        __syncthreads();
    }

    int lq = (lane >> 4) * 4;
    #pragma unroll
    for (int m = 0; m < FM; ++m) {
        #pragma unroll
        for (int n = 0; n < FN; ++n) {
            int colI = n0 + wc * WN + n * 16 + lr;
            #pragma unroll
            for (int j = 0; j < 4; ++j) {
                int rowI = m0 + wr * WM + m * 16 + lq + j;
                float v = acc[m][n][j];
                if (EPI != 0) v += bias[colI];
                if (EPI == 2) v = 0.5f * v * (1.0f + erff(v * 0.70710678118654752f));
                if (EPI == 3) v = fmaxf(v, 0.0f);
                long off = (long)rowI * N + colI;
                if (EPI == 1)      Cf[off] = v + resid[off];
                else if (EPI == 0) Cf[off] = v;
                else               Ch[off] = (bf16_t)v;
            }
        }
    }
}

// ---------------- fused attention: one block per (batch, head). T=32, HD=64.
__global__ __launch_bounds__(256) void attn_kernel(const float* __restrict__ qkv,
                                                   bf16_t* __restrict__ o) {
    int bh = blockIdx.x;
    int b  = bh >> 4;
    int hh = bh & 15;
    __shared__ float qs[32][64];
    __shared__ float kt[64][33];
    __shared__ float vs[32][64];
    __shared__ float ps[32][33];
    const float* base = qkv + (long)b * SEQ * (3 * DIM) + hh * HDIM;
    int tid = threadIdx.x;

    for (int i = tid; i < 512; i += 256) {
        int t = i >> 4;
        int c = (i & 15) << 2;
        *(float4*)&qs[t][c] = *(const float4*)(base + (long)t * 3 * DIM + c);
        float4 kv = *(const float4*)(base + (long)t * 3 * DIM + DIM + c);
        kt[c + 0][t] = kv.x;
        kt[c + 1][t] = kv.y;
        kt[c + 2][t] = kv.z;
        kt[c + 3][t] = kv.w;
        *(float4*)&vs[t][c] = *(const float4*)(base + (long)t * 3 * DIM + 2 * DIM + c);
    }
    __syncthreads();

    for (int i = tid; i < 1024; i += 256) {
        int r = i >> 5, c = i & 31;
        float acc = 0.f;
        #pragma unroll
        for (int d = 0; d < 64; ++d) acc = fmaf(qs[r][d], kt[d][c], acc);
        ps[r][c] = acc * 0.125f;
    }
    __syncthreads();

    if (tid < 32) {
        float mx = -1e30f;
        for (int c = 0; c < 32; ++c) mx = fmaxf(mx, ps[tid][c]);
        float sum = 0.f;
        for (int c = 0; c < 32; ++c) { float e = expf(ps[tid][c] - mx); ps[tid][c] = e; sum += e; }
        float inv = 1.f / sum;
        for (int c = 0; c < 32; ++c) ps[tid][c] *= inv;
    }
    __syncthreads();

    for (int i = tid; i < 2048; i += 256) {
        int r = i >> 6, d = i & 63;
        float acc = 0.f;
        #pragma unroll
        for (int c = 0; c < 32; ++c) acc = fmaf(ps[r][c], vs[c][d], acc);
        o[(long)b * SEQ * DIM + (long)r * DIM + hh * HDIM + d] = (bf16_t)acc;
    }
}

// ---------------- x_comb -> bf16
__global__ void comb_kernel(const float* __restrict__ h, bf16_t* __restrict__ xc) {
    int i = blockIdx.x * 256 + threadIdx.x;
    int b = i >> 11;
    int c = i & 2047;
    xc[i] = (bf16_t)h[(long)b * (SEQ * DIM) + c];
}

// ---------------- head layer 3: one wave per (n, b), dot-512
__global__ __launch_bounds__(256) void head3_kernel(const bf16_t* __restrict__ h2,
                                                    const float* __restrict__ w3,
                                                    const float* __restrict__ b3,
                                                    float* __restrict__ out) {
    int gid  = blockIdx.x * 256 + threadIdx.x;
    int wave = gid >> 6;
    int lane = gid & 63;
    if (wave >= NHEAD_OUT * BATCH) return;
    int n = wave >> 6;
    int b = wave & 63;
    const bf16_t* a = h2 + ((long)n * BATCH + b) * IDH;
    const float*  w = w3 + (long)n * IDH;
    float acc = 0.f;
    #pragma unroll
    for (int i = lane; i < IDH; i += 64) acc = fmaf((float)a[i], w[i], acc);
    #pragma unroll
    for (int off = 32; off > 0; off >>= 1) acc += __shfl_down(acc, off);
    if (lane == 0) out[b * NHEAD_OUT + n] = acc + b3[n];
}

extern "C" void kernel_launch(void* const* d_in, const int* in_sizes, int n_in,
                              void* d_out, int out_size, void* d_ws, size_t ws_size,
                              hipStream_t stream) {
    const float* x      = (const float*)d_in[0];
    const float* qkv_w  = (const float*)d_in[1];
    const float* out_w  = (const float*)d_in[2];
    const float* out_b  = (const float*)d_in[3];
    const float* attn_g = (const float*)d_in[4];
    const float* attn_b = (const float*)d_in[5];
    const float* ff_g   = (const float*)d_in[6];
    const float* ff_b   = (const float*)d_in[7];
    const float* ff_w1  = (const float*)d_in[8];
    const float* ff_b1  = (const float*)d_in[9];
    const float* ff_w2  = (const float*)d_in[10];
    const float* ff_b2  = (const float*)d_in[11];
    const float* hw1    = (const float*)d_in[12];
    const float* hb1    = (const float*)d_in[13];
    const float* hw2    = (const float*)d_in[14];
    const float* hb2    = (const float*)d_in[15];
    const float* hw3    = (const float*)d_in[16];
    const float* hb3    = (const float*)d_in[17];
    float* out = (float*)d_out;

    char* p = (char*)d_ws;
    float*  h     = (float*)p;            p += (long)TOK * DIM * 4;
    float*  qkvb  = (float*)p;            p += (long)TOK * 3 * DIM * 4;
    bf16_t* y     = (bf16_t*)p;           p += (long)TOK * DIM * 2;
    bf16_t* ob    = (bf16_t*)p;           p += (long)TOK * DIM * 2;
    bf16_t* ffb   = (bf16_t*)p;           p += (long)TOK * FFD * 2;
    bf16_t* xc    = (bf16_t*)p;           p += (long)BATCH * 2 * DIM * 2;
    bf16_t* h1    = (bf16_t*)p;           p += (long)NHEAD_OUT * BATCH * IDH * 2;
    bf16_t* h2    = (bf16_t*)p;           p += (long)NHEAD_OUT * BATCH * IDH * 2;
    bf16_t* qkvwt = (bf16_t*)p;           p += (long)LAYERS * DIM * 3 * DIM * 2;
    bf16_t* outwt = (bf16_t*)p;           p += (long)LAYERS * DIM * DIM * 2;
    bf16_t* ff1t  = (bf16_t*)p;           p += (long)LAYERS * DIM * FFD * 2;
    bf16_t* ff2t  = (bf16_t*)p;           p += (long)LAYERS * FFD * DIM * 2;
    bf16_t* hw1t  = (bf16_t*)p;           p += (long)NHEAD_OUT * 2 * DIM * IDH * 2;
    bf16_t* hw2t  = (bf16_t*)p;           p += (long)NHEAD_OUT * IDH * IDH * 2;

    // ---- one-time (per call) weight transpose+convert ----
    transpose_cvt<<<dim3(3 * DIM / 32, DIM / 32, LAYERS), 256, 0, stream>>>(qkv_w, qkvwt, DIM, 3 * DIM);
    transpose_cvt<<<dim3(DIM / 32, DIM / 32, LAYERS), 256, 0, stream>>>(out_w, outwt, DIM, DIM);
    transpose_cvt<<<dim3(FFD / 32, DIM / 32, LAYERS), 256, 0, stream>>>(ff_w1, ff1t, DIM, FFD);
    transpose_cvt<<<dim3(DIM / 32, FFD / 32, LAYERS), 256, 0, stream>>>(ff_w2, ff2t, FFD, DIM);
    transpose_cvt<<<dim3(IDH / 32, 2 * DIM / 32, NHEAD_OUT), 256, 0, stream>>>(hw1, hw1t, 2 * DIM, IDH);
    transpose_cvt<<<dim3(IDH / 32, IDH / 32, NHEAD_OUT), 256, 0, stream>>>(hw2, hw2t, IDH, IDH);

    hipMemcpyAsync(h, x, (size_t)TOK * DIM * sizeof(float),
                   hipMemcpyDeviceToDevice, stream);

    for (int l = 0; l < LAYERS; ++l) {
        ln_kernel<true><<<TOK, 256, 0, stream>>>(h, attn_g + l * DIM, attn_b + l * DIM, y);
        gemm_bt<128, 128, 64, 64, 0><<<dim3(3 * DIM / 128, TOK / 128), 256, 0, stream>>>(
            y, qkvwt + (long)l * DIM * 3 * DIM, nullptr, nullptr, qkvb,
            TOK, 3 * DIM, DIM, 0, 0, 0, 0);
        attn_kernel<<<BATCH * NH, 256, 0, stream>>>(qkvb, ob);
        gemm_bt<64, 128, 32, 64, 1><<<dim3(DIM / 128, TOK / 64), 256, 0, stream>>>(
            ob, outwt + (long)l * DIM * DIM, out_b + l * DIM, h, h,
            TOK, DIM, DIM, 0, 0, 0, 0);
        ln_kernel<false><<<TOK, 256, 0, stream>>>(h, ff_g + l * DIM, ff_b + l * DIM, y);
        gemm_bt<128, 128, 64, 64, 2><<<dim3(FFD / 128, TOK / 128), 256, 0, stream>>>(
            y, ff1t + (long)l * DIM * FFD, ff_b1 + l * FFD, nullptr, ffb,
            TOK, FFD, DIM, 0, 0, 0, 0);
        gemm_bt<64, 128, 32, 64, 1><<<dim3(DIM / 128, TOK / 64), 256, 0, stream>>>(
            ffb, ff2t + (long)l * FFD * DIM, ff_b2 + l * DIM, h, h,
            TOK, DIM, FFD, 0, 0, 0, 0);
    }

    comb_kernel<<<(BATCH * 2 * DIM) / 256, 256, 0, stream>>>(h, xc);

    gemm_bt<64, 64, 32, 32, 3><<<dim3(IDH / 64, 1, NHEAD_OUT), 256, 0, stream>>>(
        xc, hw1t, hb1, nullptr, h1,
        BATCH, IDH, 2 * DIM,
        0, (long)2 * DIM * IDH, IDH, (long)BATCH * IDH);
    gemm_bt<64, 64, 32, 32, 3><<<dim3(IDH / 64, 1, NHEAD_OUT), 256, 0, stream>>>(
        h1, hw2t, hb2, nullptr, h2,
        BATCH, IDH, IDH,
        (long)BATCH * IDH, (long)IDH * IDH, IDH, (long)BATCH * IDH);
    head3_kernel<<<(NHEAD_OUT * BATCH * 64) / 256, 256, 0, stream>>>(h2, hw3, hb3, out);
}